// Round 18
// baseline (1207.931 us; speedup 1.0000x reference)
//
#include <hip/hip_runtime.h>
#include <hip/hip_bf16.h>

typedef unsigned short u16;
typedef short bf16x8 __attribute__((ext_vector_type(8)));
typedef float f32x4 __attribute__((ext_vector_type(4)));

#define SCALE_F 0.08838834764831845f

// VEC offsets (u16 elems)
#define VC_PW    0
#define VC_PB    1408
#define VC_N1W   1536
#define VC_N1B   1792
#define VC_QKVB  2048
#define VC_PROJB 2816
#define VC_N2W   3072
#define VC_N2B   3328
#define VC_B1    3584
#define VC_B2    4608
#define VC_NFW   4864
#define VC_NFB   4992
#define VC_RPB   5120
#define VC_OW    6592
#define VC_OBIAS 44480

// WT offsets (u16 elems) — transposed weights [N][K]
#define WT_QKV  0
#define WT_PROJ 98304
#define WT_W1   131072
#define WT_W2   262144

// MLP LDS: Wbuf parity R18 — chunk 0 lives in sC (written right after barrier 4,
// where the V-stash dies); even steps read sC, odd read sA[0,8192). sH = sA[8192,13312)
// stride-40. b1/b2 read from global (R16 LDS-staging reverted: null result + blocks this).
#define SH_OFF  8192

__device__ __forceinline__ float bf2f(u16 x) {
  union { unsigned int i; float f; } v; v.i = ((unsigned int)x) << 16; return v.f;
}
// HW bf16 convert (RTNE): compiler lowers pairs to v_cvt_pk_bf16_f32 (guide m240).
__device__ __forceinline__ u16 f2bf(float f) {
  __hip_bfloat16 h = __float2bfloat16(f);
  return __builtin_bit_cast(u16, h);
}
__device__ __forceinline__ unsigned int packbf(float a, float b) {
  return (unsigned int)f2bf(a) | ((unsigned int)f2bf(b) << 16);
}
__device__ __forceinline__ float wsum(float v) {
#pragma unroll
  for (int m = 32; m >= 1; m >>= 1) v += __shfl_xor(v, m, 64);
  return v;
}
// gelu with exp folded into exp2 (v_exp_f32 is native exp2).
__device__ __forceinline__ float gelu_f(float x) {
  float u = x * (-2.3022078f - 0.1029432f * x * x);
  float e = exp2f(u);
  return x * __builtin_amdgcn_rcpf(1.f + e);
}

// -------- dtype scan + decide (R18: fused, LDS accumulators) --------
__global__ __launch_bounds__(256) void k_scan(const u16* __restrict__ raw, int* __restrict__ flag) {
  __shared__ int snan, sez;
  if (threadIdx.x == 0) { snan = 0; sez = 0; }
  __syncthreads();
  int nanc = 0, ez = 0;
  for (int i = threadIdx.x; i < 131072; i += 256) {
    u16 x = raw[i];
    if ((x & 0x7F80u) == 0x7F80u) nanc++;
    if (!(i & 1) && x == 0) ez++;
  }
  atomicAdd(&snan, nanc);
  atomicAdd(&sez, ez);
  __syncthreads();
  if (threadIdx.x == 0) flag[0] = (snan > 0 || sez > 49152) ? 1 : 0;
}

// -------- dual-mode converts --------
__global__ __launch_bounds__(256) void k_conv(const void* __restrict__ src, u16* __restrict__ dst,
                                              int n, const int* __restrict__ flag) {
  const int fl = *flag;
  int i = blockIdx.x * 256 + threadIdx.x;
  if (i < n) dst[i] = fl ? f2bf(((const float*)src)[i]) : ((const u16*)src)[i];
}
// all 15 small VEC conversions in ONE launch (grid.y = segment).
struct CvTab { const void* src[15]; int off[15]; int n[15]; };
__global__ __launch_bounds__(256) void k_convb(CvTab t, u16* __restrict__ dst,
                                               const int* __restrict__ flag) {
  const int fl = *flag;
  const int s = blockIdx.y;
  const int i = blockIdx.x * 256 + threadIdx.x;
  if (i < t.n[s]) {
    const void* src = t.src[s];
    dst[t.off[s] + i] = fl ? f2bf(((const float*)src)[i]) : ((const u16*)src)[i];
  }
}
// R18: all 8 transposed-weight conversions in ONE launch (grid.y = segment).
struct CtTab { const void* src[8]; int K[8]; int N[8]; int eoff[8]; int doff[8]; };
__global__ __launch_bounds__(256) void k_convT2b(CtTab t, u16* __restrict__ WT,
                                                 const int* __restrict__ flag) {
  const int fl = *flag;
  const int s = blockIdx.y;
  const int id = blockIdx.x * 256 + threadIdx.x;
  const int K = t.K[s];
  if (id < K * t.N[s]) {
    int n = id / K, k = id % K;
    const void* src = t.src[s];
    int e = t.eoff[s] + k * t.N[s] + n;
    WT[t.doff[s] + id] = fl ? f2bf(((const float*)src)[e]) : ((const u16*)src)[e];
  }
}

// -------- precomputed attention bias tables --------
// TRANSPOSED layout MT[w][q*128+j]. w=96 -> layer 0.
__global__ __launch_bounds__(256) void k_mask(const u16* __restrict__ vec, u16* __restrict__ MT) {
  const int w = blockIdx.x;            // 0..95: layer-1 windows; 96: layer 0
  const bool bnd = (w < 96);
  const u16* rpb = vec + VC_RPB + (bnd ? 729 : 0);
  int wd = 0, wh = 0, ww = 0;
  if (bnd) { wd = w / 48; wh = (w >> 3) % 6; ww = w & 7; }
  for (int e = threadIdx.x; e < 16384; e += 256) {
    int j = e & 127, q = e >> 7;       // e = q*128 + j
    int qc = q > 124 ? 124 : q, jc = j > 124 ? 124 : j;
    int ldq = qc / 25, lhq = (qc / 5) % 5, lwq = qc % 5;
    int ldk = jc / 25, lhk = (jc / 5) % 5, lwk = jc % 5;
    float s = bf2f(rpb[((ldq - ldk + 4) * 9 + (lhq - lhk + 4)) * 9 + (lwq - lwk + 4)]);
    if (ldq < ldk) s -= 100.f;
    if (bnd) {
      int gdq = wd * 5 + ldq, ghq = wh * 5 + lhq, gwq = ww * 5 + lwq;
      int gdk = wd * 5 + ldk, ghk = wh * 5 + lhk, gwk = ww * 5 + lwk;
      int rq = (gdq < 5 ? 0 : (gdq < 8 ? 1 : 2)) * 9 + (ghq < 25 ? 0 : (ghq < 28 ? 1 : 2)) * 3 +
               (gwq < 35 ? 0 : (gwq < 38 ? 1 : 2));
      int rk = (gdk < 5 ? 0 : (gdk < 8 ? 1 : 2)) * 9 + (ghk < 25 ? 0 : (ghk < 28 ? 1 : 2)) * 3 +
               (gwk < 35 ? 0 : (gwk < 38 ? 1 : 2));
      if (rq != rk) s -= 100.f;
    }
    MT[(size_t)w * 16384 + e] = f2bf(s);
  }
}

// ---------------- patch embed (paired-channel outputs, 4B packed stores) ----------------
__global__ __launch_bounds__(256) void k_patch(const u16* __restrict__ obs,
                                               const u16* __restrict__ vec,
                                               u16* __restrict__ X) {
  __shared__ float vis[11][40];
  __shared__ float spw[11][128];
  __shared__ float spb[128];
  const int tid = threadIdx.x;
  const int bdh = blockIdx.x;
  const int b = bdh / 300, rem = bdh % 300;
  const int d = rem / 30, h = rem % 30;
  for (int i = tid; i < 1408; i += 256) spw[i >> 7][i & 127] = bf2f(vec[VC_PW + i]);
  if (tid < 128) spb[tid] = bf2f(vec[VC_PB + tid]);
  for (int i = tid; i < 440; i += 256) {
    int ch = i / 40, w = i % 40;
    vis[ch][w] = bf2f(obs[(size_t)b * 132020 + ((d * 11 + ch) * 30 + h) * 40 + w]);
  }
  __syncthreads();
  const size_t xbase = ((size_t)b * 12000 + d * 1200 + h * 40) * 128;
  for (int o2 = tid * 2; o2 < 40 * 128; o2 += 512) {
    int w = o2 >> 7, c = o2 & 127;          // c even
    float acc0 = spb[c], acc1 = spb[c + 1];
#pragma unroll
    for (int ch = 0; ch < 11; ch++) {
      float v = vis[ch][w];
      acc0 += v * spw[ch][c];
      acc1 += v * spw[ch][c + 1];
    }
    *(unsigned int*)(X + xbase + o2) = packbf(acc0, acc1);
  }
}

// One MLP double-buffer step with STATIC buffer pointers (unroll-x2; global b1).
#define MLP_STEP(BUFC, BUFN, HC, PF) {                                                          \
    uint4 w1n, w2n;                                                                             \
    const bool pf_ = (PF);                                                                      \
    if (pf_) {                                                                                  \
      w1n = *(const uint4*)(W1T + (size_t)(((HC) + 1) * 32 + (tid >> 4)) * 128 + (tid & 15) * 8); \
      w2n = *(const uint4*)(W2T + (size_t)(tid >> 2) * 512 + ((HC) + 1) * 32 + (tid & 3) * 8);  \
    }                                                                                           \
    f32x4 h4[2];                                                                                \
    _Pragma("unroll")                                                                           \
    for (int nt = 0; nt < 2; nt++)                                                              \
      _Pragma("unroll")                                                                         \
      for (int r = 0; r < 4; r++) h4[nt][r] = 0.f;                                              \
    _Pragma("unroll")                                                                           \
    for (int kc = 0; kc < 4; kc++) {                                                            \
      _Pragma("unroll")                                                                         \
      for (int nt = 0; nt < 2; nt++) {                                                          \
        int hrow = nt * 16 + m16;                                                               \
        bf16x8 af = *(const bf16x8*)((BUFC) + hrow * 128 + (((4 * kc + quad) ^ m16) << 3));     \
        h4[nt] = __builtin_amdgcn_mfma_f32_16x16x32_bf16(af, biM[kc], h4[nt], 0, 0, 0);         \
      }                                                                                         \
    }                                                                                           \
    _Pragma("unroll")                                                                           \
    for (int nt = 0; nt < 2; nt++) {                                                            \
      int hb = nt * 16 + quad * 4;                                                              \
      float g0 = gelu_f(h4[nt][0] + bf2f(b1[(HC) * 32 + hb]));                                  \
      float g1 = gelu_f(h4[nt][1] + bf2f(b1[(HC) * 32 + hb + 1]));                              \
      float g2 = gelu_f(h4[nt][2] + bf2f(b1[(HC) * 32 + hb + 2]));                              \
      float g3 = gelu_f(h4[nt][3] + bf2f(b1[(HC) * 32 + hb + 3]));                              \
      uint2 pk;                                                                                 \
      pk.x = packbf(g0, g1);                                                                    \
      pk.y = packbf(g2, g3);                                                                    \
      *(uint2*)(sA + SH_OFF + tok * 40 + hb) = pk;                                              \
    }                                                                                           \
    {                                                                                           \
      bf16x8 bh = *(const bf16x8*)(sA + SH_OFF + tok * 40 + quad * 8);                          \
      _Pragma("unroll")                                                                         \
      for (int mt = 0; mt < 8; mt++) {                                                          \
        int oc = mt * 16 + m16;                                                                 \
        bf16x8 af = *(const bf16x8*)((BUFC) + 4096 + oc * 32 + ((quad ^ (oc & 3)) << 3));       \
        acc2[mt] = __builtin_amdgcn_mfma_f32_16x16x32_bf16(af, bh, acc2[mt], 0, 0, 0);          \
      }                                                                                         \
    }                                                                                           \
    if (pf_) {                                                                                  \
      int row_ = tid >> 4, g_ = tid & 15;                                                       \
      *(uint4*)((BUFN) + row_ * 128 + ((g_ ^ (row_ & 15)) << 3)) = w1n;                         \
      int row2_ = tid >> 2, g2_ = tid & 3;                                                      \
      *(uint4*)((BUFN) + 4096 + row2_ * 32 + ((g2_ ^ (row2_ & 3)) << 3)) = w2n;                 \
    }                                                                                           \
    __syncthreads();                                                                            \
  }

// ================== fused per-window BLOCK: LN1+QKV+attn+proj+res + LN2+MLP+res ==================
// One block per window (3072), 512 threads (8 waves), 80 KB LDS -> 2 blocks/CU.
// Channel-decomposed QKV AND proj; mask table; double-buffered MLP W; unroll-x2 MLP.
// R18: chunk-0 W loads issued before barrier 3, stored into sC (dead V-stash) right
// after barrier 4 -> latency hidden under O^T/proj/LN2; barrier 7b removed (8 barriers).
__global__ __launch_bounds__(512, 4) void k_win(u16* __restrict__ X,
                                                const u16* __restrict__ Wqkv,   // [384][128]
                                                const u16* __restrict__ Wproj,  // [128][128]
                                                const u16* __restrict__ W1T,    // [512][128]
                                                const u16* __restrict__ W2T,    // [128][512]
                                                const u16* __restrict__ qkvb,
                                                const u16* __restrict__ projb,
                                                const u16* __restrict__ n1w, const u16* __restrict__ n1b,
                                                const u16* __restrict__ n2w, const u16* __restrict__ n2b,
                                                const u16* __restrict__ b1, const u16* __restrict__ b2,
                                                const u16* __restrict__ MT,
                                                int shift, int boundary) {
  __shared__ u16 sA[128 * 128];   // Y -> K -> V^T -> proj-out -> {Wbuf-odd | sH}
  __shared__ u16 sB[128 * 128];   // Q -> P -> O -> sIn(LN2) -> mlp-out
  __shared__ uint2 sC[4 * 512];   // 16 KB: V stash (attn) -> Wbuf-even (MLP)
  u16* sCu = (u16*)sC;
  const int tid = threadIdx.x, lane = tid & 63, wv = tid >> 6;
  const int m16 = lane & 15, quad = lane >> 4;
  const int wing = blockIdx.x;
  const int b = wing / 96, winb = wing % 96;
  const int wd = winb / 48, wh = (winb >> 3) % 6, ww = winb & 7;
  const int tok = wv * 16 + m16;          // lane's token (0..127)
  const int tokc = tok > 124 ? 124 : tok;
  const u16* mtab = MT + (size_t)(boundary ? winb : 96) * 16384;

  // ---- LN1 + roll + gather: 4-row batches, 8 interleaved butterfly chains ----
  const float nw0 = bf2f(n1w[2 * lane]), nb0 = bf2f(n1b[2 * lane]);
  const float nw1 = bf2f(n1w[2 * lane + 1]), nb1 = bf2f(n1b[2 * lane + 1]);
  for (int rb = 0; rb < 16; rb += 4) {
    unsigned int uu[4];
    float s0[4], s1[4];
#pragma unroll
    for (int i = 0; i < 4; i++) {
      int row = wv * 16 + rb + i;
      int n = row > 124 ? 124 : row;
      int ld = n / 25, lh = (n / 5) % 5, lw = n % 5;
      int d = wd * 5 + ld + shift; if (d >= 10) d -= 10;
      int h = wh * 5 + lh + shift; if (h >= 30) h -= 30;
      int w2 = ww * 5 + lw + shift; if (w2 >= 40) w2 -= 40;
      const u16* xp = X + ((((size_t)b * 10 + d) * 30 + h) * 40 + w2) * 128;
      uu[i] = *(const unsigned int*)(xp + 2 * lane);
    }
#pragma unroll
    for (int i = 0; i < 4; i++) {
      float x0 = bf2f((u16)(uu[i] & 0xffff)), x1 = bf2f((u16)(uu[i] >> 16));
      s0[i] = x0 + x1;
      s1[i] = x0 * x0 + x1 * x1;
    }
#pragma unroll
    for (int m = 32; m >= 1; m >>= 1) {
#pragma unroll
      for (int i = 0; i < 4; i++) {
        s0[i] += __shfl_xor(s0[i], m, 64);
        s1[i] += __shfl_xor(s1[i], m, 64);
      }
    }
#pragma unroll
    for (int i = 0; i < 4; i++) {
      int r = rb + i;
      int row = wv * 16 + r;
      float mean = s0[i] * (1.f / 128.f);
      float var = s1[i] * (1.f / 128.f) - mean * mean;
      float rstd = rsqrtf(var + 1e-5f);
      float x0 = bf2f((u16)(uu[i] & 0xffff)), x1 = bf2f((u16)(uu[i] >> 16));
      float y0 = (x0 - mean) * rstd * nw0 + nb0;
      float y1 = (x1 - mean) * rstd * nw1 + nb1;
      *(unsigned int*)(sA + row * 128 + (((lane >> 2) ^ r) << 3) + ((2 * lane) & 7)) =
          packbf(y0, y1);
    }
  }
  __syncthreads();  // barrier 0: Y visible to all waves (channel-dec reads all rows)

  // ---- V (channel tile wv, all tokens): tt 0..3 -> sC stash, tt 4..7 -> vreg ----
  uint2 vreg[4];
  {
    bf16x8 aV[4];
#pragma unroll
    for (int kc = 0; kc < 4; kc++)
      aV[kc] = *(const bf16x8*)(Wqkv + (size_t)(256 + wv * 16 + m16) * 128 + kc * 32 + quad * 8);
    const int oc = 256 + wv * 16 + quad * 4;
    const float b0 = bf2f(qkvb[oc]), b1v = bf2f(qkvb[oc + 1]);
    const float b2v = bf2f(qkvb[oc + 2]), b3 = bf2f(qkvb[oc + 3]);
#pragma unroll
    for (int tt = 0; tt < 8; tt++) {
      f32x4 acc; acc[0] = 0.f; acc[1] = 0.f; acc[2] = 0.f; acc[3] = 0.f;
      int brow = tt * 16 + m16;
#pragma unroll
      for (int kc = 0; kc < 4; kc++) {
        bf16x8 bfr = *(const bf16x8*)(sA + brow * 128 + (((4 * kc + quad) ^ m16) << 3));
        acc = __builtin_amdgcn_mfma_f32_16x16x32_bf16(aV[kc], bfr, acc, 0, 0, 0);
      }
      uint2 pk;
      pk.x = packbf(acc[0] + b0, acc[1] + b1v);
      pk.y = packbf(acc[2] + b2v, acc[3] + b3);
      if (tt < 4) sC[tt * 512 + tid] = pk;
      else vreg[tt - 4] = pk;
    }
  }
  // ---- Q (channel tile wv, all tokens, scaled) -> sB[tok][wv-block] ----
  {
    bf16x8 aQ[4];
#pragma unroll
    for (int kc = 0; kc < 4; kc++)
      aQ[kc] = *(const bf16x8*)(Wqkv + (size_t)(wv * 16 + m16) * 128 + kc * 32 + quad * 8);
    const int oc = wv * 16 + quad * 4;
    const float b0 = bf2f(qkvb[oc]), b1v = bf2f(qkvb[oc + 1]);
    const float b2v = bf2f(qkvb[oc + 2]), b3 = bf2f(qkvb[oc + 3]);
#pragma unroll
    for (int tt = 0; tt < 8; tt++) {
      f32x4 acc; acc[0] = 0.f; acc[1] = 0.f; acc[2] = 0.f; acc[3] = 0.f;
      int brow = tt * 16 + m16;
#pragma unroll
      for (int kc = 0; kc < 4; kc++) {
        bf16x8 bfr = *(const bf16x8*)(sA + brow * 128 + (((4 * kc + quad) ^ m16) << 3));
        acc = __builtin_amdgcn_mfma_f32_16x16x32_bf16(aQ[kc], bfr, acc, 0, 0, 0);
      }
      uint2 pk;
      pk.x = packbf((acc[0] + b0) * SCALE_F, (acc[1] + b1v) * SCALE_F);
      pk.y = packbf((acc[2] + b2v) * SCALE_F, (acc[3] + b3) * SCALE_F);
      *(uint2*)(sB + brow * 128 + (((2 * wv + (quad >> 1)) ^ m16) << 3) + ((quad & 1) << 2)) = pk;
    }
  }
  // ---- K (channel tile wv, all tokens) -> kreg[8] (stored to sA after Y-reads barrier) ----
  uint2 kreg[8];
  {
    bf16x8 aK[4];
#pragma unroll
    for (int kc = 0; kc < 4; kc++)
      aK[kc] = *(const bf16x8*)(Wqkv + (size_t)(128 + wv * 16 + m16) * 128 + kc * 32 + quad * 8);
    const int oc = 128 + wv * 16 + quad * 4;
    const float b0 = bf2f(qkvb[oc]), b1v = bf2f(qkvb[oc + 1]);
    const float b2v = bf2f(qkvb[oc + 2]), b3 = bf2f(qkvb[oc + 3]);
#pragma unroll
    for (int tt = 0; tt < 8; tt++) {
      f32x4 acc; acc[0] = 0.f; acc[1] = 0.f; acc[2] = 0.f; acc[3] = 0.f;
      int brow = tt * 16 + m16;
#pragma unroll
      for (int kc = 0; kc < 4; kc++) {
        bf16x8 bfr = *(const bf16x8*)(sA + brow * 128 + (((4 * kc + quad) ^ m16) << 3));
        acc = __builtin_amdgcn_mfma_f32_16x16x32_bf16(aK[kc], bfr, acc, 0, 0, 0);
      }
      kreg[tt].x = packbf(acc[0] + b0, acc[1] + b1v);
      kreg[tt].y = packbf(acc[2] + b2v, acc[3] + b3);
    }
  }
  __syncthreads();  // barrier 1: all waves done reading Y from sA
  // ---- K store: sA[tok][wv-block] (overwrites Y) ----
#pragma unroll
  for (int tt = 0; tt < 8; tt++) {
    int brow = tt * 16 + m16;
    *(uint2*)(sA + brow * 128 + (((2 * wv + (quad >> 1)) ^ m16) << 3) + ((quad & 1) << 2)) = kreg[tt];
  }
  __syncthreads();  // barrier 2: K (and Q) visible to all waves

  // ---- S^T = K·Q^T ----
  f32x4 S[8];
#pragma unroll
  for (int jt = 0; jt < 8; jt++) { S[jt][0] = 0.f; S[jt][1] = 0.f; S[jt][2] = 0.f; S[jt][3] = 0.f; }
#pragma unroll
  for (int kc = 0; kc < 4; kc++) {
    bf16x8 qf = *(const bf16x8*)(sB + tok * 128 + (((4 * kc + quad) ^ m16) << 3));
#pragma unroll
    for (int jt = 0; jt < 8; jt++) {
      int row = jt * 16 + m16;
      bf16x8 kf = *(const bf16x8*)(sA + row * 128 + (((4 * kc + quad) ^ m16) << 3));
      S[jt] = __builtin_amdgcn_mfma_f32_16x16x32_bf16(kf, qf, S[jt], 0, 0, 0);
    }
  }
  // ---- bias from transposed table (uint2 loads) + softmax ----
  float mx = -1e30f;
#pragma unroll
  for (int jt = 0; jt < 8; jt++) {
    uint2 mv = *(const uint2*)(mtab + tokc * 128 + jt * 16 + quad * 4);
    u16 mb0 = (u16)(mv.x & 0xffff), mb1 = (u16)(mv.x >> 16);
    u16 mb2 = (u16)(mv.y & 0xffff), mb3 = (u16)(mv.y >> 16);
    float sv0 = S[jt][0] + bf2f(mb0);
    float sv1 = S[jt][1] + bf2f(mb1);
    float sv2 = S[jt][2] + bf2f(mb2);
    float sv3 = S[jt][3] + bf2f(mb3);
    int j0 = jt * 16 + quad * 4;
    if (j0 + 0 >= 125) sv0 = -1e30f;
    if (j0 + 1 >= 125) sv1 = -1e30f;
    if (j0 + 2 >= 125) sv2 = -1e30f;
    if (j0 + 3 >= 125) sv3 = -1e30f;
    S[jt][0] = sv0; S[jt][1] = sv1; S[jt][2] = sv2; S[jt][3] = sv3;
    mx = fmaxf(mx, fmaxf(fmaxf(sv0, sv1), fmaxf(sv2, sv3)));
  }
  mx = fmaxf(mx, __shfl_xor(mx, 16, 64));
  mx = fmaxf(mx, __shfl_xor(mx, 32, 64));
  float sm = 0.f;
#pragma unroll
  for (int jt = 0; jt < 8; jt++)
#pragma unroll
    for (int r = 0; r < 4; r++) {
      float e = __expf(S[jt][r] - mx);
      S[jt][r] = e;
      sm += e;
    }
  sm += __shfl_xor(sm, 16, 64);
  sm += __shfl_xor(sm, 32, 64);
  float inv = 1.f / sm;
  // P -> sB own rows (overwrites own Q)
#pragma unroll
  for (int jt = 0; jt < 8; jt++) {
    uint2 pk;
    pk.x = packbf(S[jt][0] * inv, S[jt][1] * inv);
    pk.y = packbf(S[jt][2] * inv, S[jt][3] * inv);
    *(uint2*)(sB + tok * 128 + (((2 * jt + (quad >> 1)) ^ m16) << 3) + ((quad & 1) << 2)) = pk;
  }
  // ---- issue W chunk-0 global loads (land during barrier/scatter; stored post-barrier-4) ----
  uint4 w1r = *(const uint4*)(W1T + (size_t)(tid >> 4) * 128 + (tid & 15) * 8);
  uint4 w2r = *(const uint4*)(W2T + (size_t)(tid >> 2) * 512 + (tid & 3) * 8);
  __syncthreads();  // barrier 3: all waves done reading sA (K)
  // ---- V^T scatter into sA (overwrites K); consumes sC V-stash ----
#pragma unroll
  for (int tt = 0; tt < 8; tt++) {
    uint2 vv = (tt < 4) ? sC[tt * 512 + tid] : vreg[tt - 4];
    int tokv = tt * 16 + m16;
    int c0 = wv * 16 + quad * 4;
    sA[(c0 + 0) * 128 + ((((tokv >> 3) ^ ((c0 + 0) & 15))) << 3) + (tokv & 7)] = (u16)(vv.x & 0xffffu);
    sA[(c0 + 1) * 128 + ((((tokv >> 3) ^ ((c0 + 1) & 15))) << 3) + (tokv & 7)] = (u16)(vv.x >> 16);
    sA[(c0 + 2) * 128 + ((((tokv >> 3) ^ ((c0 + 2) & 15))) << 3) + (tokv & 7)] = (u16)(vv.y & 0xffffu);
    sA[(c0 + 3) * 128 + ((((tokv >> 3) ^ ((c0 + 3) & 15))) << 3) + (tokv & 7)] = (u16)(vv.y >> 16);
  }
  __syncthreads();  // barrier 4: V^T visible; sC (V-stash) now dead
  // ---- W chunk 0 -> sC (visible to MLP step 0 via barriers 5-7) ----
  {
    int row = tid >> 4, g = tid & 15;
    *(uint4*)(sCu + row * 128 + ((g ^ (row & 15)) << 3)) = w1r;
    int row2 = tid >> 2, g2 = tid & 3;
    *(uint4*)(sCu + 4096 + row2 * 32 + ((g2 ^ (row2 & 3)) << 3)) = w2r;
  }
  // ---- O^T = VT·P ----
  f32x4 O[8];
#pragma unroll
  for (int ct = 0; ct < 8; ct++) { O[ct][0] = 0.f; O[ct][1] = 0.f; O[ct][2] = 0.f; O[ct][3] = 0.f; }
#pragma unroll
  for (int kc = 0; kc < 4; kc++) {
    bf16x8 pf = *(const bf16x8*)(sB + tok * 128 + (((4 * kc + quad) ^ m16) << 3));
#pragma unroll
    for (int ct = 0; ct < 8; ct++) {
      int c = ct * 16 + m16;
      bf16x8 vf = *(const bf16x8*)(sA + c * 128 + (((4 * kc + quad) ^ m16) << 3));
      O[ct] = __builtin_amdgcn_mfma_f32_16x16x32_bf16(vf, pf, O[ct], 0, 0, 0);
    }
  }
  // O -> sB own rows (overwrites own P) BEFORE barrier 5, so barrier 5 publishes O
#pragma unroll
  for (int ct = 0; ct < 8; ct++) {
    uint2 pk;
    pk.x = packbf(O[ct][0], O[ct][1]);
    pk.y = packbf(O[ct][2], O[ct][3]);
    *(uint2*)(sB + tok * 128 + (((2 * ct + (quad >> 1)) ^ m16) << 3) + ((quad & 1) << 2)) = pk;
  }
  __syncthreads();  // barrier 5: sA (V^T) reads done AND O (sB) visible to all waves

  // ---- proj (channel tile wv, all tokens) -> sA[tok][wv-block] (overwrites V^T) ----
  {
    bf16x8 aP[4];
#pragma unroll
    for (int kc = 0; kc < 4; kc++)
      aP[kc] = *(const bf16x8*)(Wproj + (size_t)(wv * 16 + m16) * 128 + kc * 32 + quad * 8);
    const int oc = wv * 16 + quad * 4;
    const float b0 = bf2f(projb[oc]), b1v = bf2f(projb[oc + 1]);
    const float b2v = bf2f(projb[oc + 2]), b3 = bf2f(projb[oc + 3]);
#pragma unroll
    for (int tt = 0; tt < 8; tt++) {
      f32x4 acc; acc[0] = 0.f; acc[1] = 0.f; acc[2] = 0.f; acc[3] = 0.f;
      int brow = tt * 16 + m16;
#pragma unroll
      for (int kc = 0; kc < 4; kc++) {
        bf16x8 bfr = *(const bf16x8*)(sB + brow * 128 + (((4 * kc + quad) ^ m16) << 3));
        acc = __builtin_amdgcn_mfma_f32_16x16x32_bf16(aP[kc], bfr, acc, 0, 0, 0);
      }
      uint2 pk;
      pk.x = packbf(acc[0] + b0, acc[1] + b1v);
      pk.y = packbf(acc[2] + b2v, acc[3] + b3);
      *(uint2*)(sA + brow * 128 + (((2 * wv + (quad >> 1)) ^ m16) << 3) + ((quad & 1) << 2)) = pk;
    }
  }
  __syncthreads();  // barrier 6: proj-out (sA) visible to all waves

  // ---- fused epilogue: residual write + LN2 -> sIn(sB), 4-row batches ----
  const float w20 = bf2f(n2w[2 * lane]), v20 = bf2f(n2b[2 * lane]);
  const float w21 = bf2f(n2w[2 * lane + 1]), v21 = bf2f(n2b[2 * lane + 1]);
  for (int rb = 0; rb < 16; rb += 4) {
    float xn0[4], xn1[4], s0[4], s1[4];
#pragma unroll
    for (int i = 0; i < 4; i++) {
      int r = rb + i, row = wv * 16 + r;
      int n = row > 124 ? 124 : row;
      int ld = n / 25, lh = (n / 5) % 5, lw = n % 5;
      int d = wd * 5 + ld + shift; if (d >= 10) d -= 10;
      int h = wh * 5 + lh + shift; if (h >= 30) h -= 30;
      int w2 = ww * 5 + lw + shift; if (w2 >= 40) w2 -= 40;
      u16* xp = X + ((((size_t)b * 10 + d) * 30 + h) * 40 + w2) * 128;
      unsigned int pv = *(const unsigned int*)(sA + row * 128 + (((lane >> 2) ^ r) << 3) + ((2 * lane) & 7));
      unsigned int xo = *(const unsigned int*)(xp + 2 * lane);
      xn0[i] = bf2f((u16)(xo & 0xffff)) + bf2f((u16)(pv & 0xffff));
      xn1[i] = bf2f((u16)(xo >> 16)) + bf2f((u16)(pv >> 16));
      if (row < 125) *(unsigned int*)(xp + 2 * lane) = packbf(xn0[i], xn1[i]);
      s0[i] = xn0[i] + xn1[i];
      s1[i] = xn0[i] * xn0[i] + xn1[i] * xn1[i];
    }
#pragma unroll
    for (int m = 32; m >= 1; m >>= 1) {
#pragma unroll
      for (int i = 0; i < 4; i++) {
        s0[i] += __shfl_xor(s0[i], m, 64);
        s1[i] += __shfl_xor(s1[i], m, 64);
      }
    }
#pragma unroll
    for (int i = 0; i < 4; i++) {
      int r = rb + i, row = wv * 16 + r;
      float mean = s0[i] * (1.f / 128.f);
      float var = s1[i] * (1.f / 128.f) - mean * mean;
      float rstd = rsqrtf(var + 1e-5f);
      float y0 = (xn0[i] - mean) * rstd * w20 + v20;
      float y1 = (xn1[i] - mean) * rstd * w21 + v21;
      *(unsigned int*)(sB + row * 128 + (((lane >> 2) ^ r) << 3) + ((2 * lane) & 7)) =
          packbf(y0, y1);
    }
  }
  // ---- hoist MLP input fragments (own rows of sB; loop-invariant across hc) ----
  bf16x8 biM[4];
#pragma unroll
  for (int kc = 0; kc < 4; kc++)
    biM[kc] = *(const bf16x8*)(sB + tok * 128 + (((4 * kc + quad) ^ m16) << 3));
  __syncthreads();  // barrier 7: all sA (proj) reads done -> sA reusable (sH + Wbuf-odd)

  // ---- MLP main loop: HC=32, 16 steps unrolled x2; chunk 0 already in sC ----
  f32x4 acc2[8];
#pragma unroll
  for (int mt = 0; mt < 8; mt++)
#pragma unroll
    for (int r = 0; r < 4; r++) acc2[mt][r] = 0.f;
  for (int hc2 = 0; hc2 < 8; hc2++) {
    MLP_STEP(sCu, sA, 2 * hc2, true);
    MLP_STEP(sA, sCu, 2 * hc2 + 1, (hc2 < 7));
  }
  // ---- mlp-out (+bias) -> sB own rows; final residual RMW (rolled, guarded) ----
#pragma unroll
  for (int mt = 0; mt < 8; mt++) {
    int oc = mt * 16 + quad * 4;
    uint2 pk;
    pk.x = packbf(acc2[mt][0] + bf2f(b2[oc]), acc2[mt][1] + bf2f(b2[oc + 1]));
    pk.y = packbf(acc2[mt][2] + bf2f(b2[oc + 2]), acc2[mt][3] + bf2f(b2[oc + 3]));
    *(uint2*)(sB + tok * 128 + (((2 * mt + (quad >> 1)) ^ m16) << 3) + ((quad & 1) << 2)) = pk;
  }
  for (int r = 0; r < 16; r++) {
    int row = wv * 16 + r;
    if (row > 124) break;               // rows 125..127 duplicate token 124 (discard)
    int ld = row / 25, lh = (row / 5) % 5, lw = row % 5;
    int d = wd * 5 + ld + shift; if (d >= 10) d -= 10;
    int h = wh * 5 + lh + shift; if (h >= 30) h -= 30;
    int w2 = ww * 5 + lw + shift; if (w2 >= 40) w2 -= 40;
    u16* xp = X + ((((size_t)b * 10 + d) * 30 + h) * 40 + w2) * 128;
    unsigned int pv = *(const unsigned int*)(sB + row * 128 + (((lane >> 2) ^ r) << 3) + ((2 * lane) & 7));
    unsigned int xo = *(const unsigned int*)(xp + 2 * lane);
    float o0 = bf2f((u16)(xo & 0xffff)) + bf2f((u16)(pv & 0xffff));
    float o1 = bf2f((u16)(xo >> 16)) + bf2f((u16)(pv >> 16));
    *(unsigned int*)(xp + 2 * lane) = packbf(o0, o1);
  }
}

// ---------------- final LN + partial pooling (240-token slices, grid 1600) ----------------
__global__ __launch_bounds__(256) void k_pool(const u16* __restrict__ X, const u16* __restrict__ vec,
                                              float* __restrict__ pool) {
  __shared__ float sacc[4][128];
  const int tid = threadIdx.x, lane = tid & 63, wv = tid >> 6;
  const int b = blockIdx.x / 50, slice = blockIdx.x % 50;
  const float nw0 = bf2f(vec[VC_NFW + 2 * lane]), nb0 = bf2f(vec[VC_NFB + 2 * lane]);
  const float nw1 = bf2f(vec[VC_NFW + 2 * lane + 1]), nb1 = bf2f(vec[VC_NFB + 2 * lane + 1]);
  float a0 = 0.f, a1 = 0.f;
  for (int tb = wv; tb < 240; tb += 16) {      // 4 rows per batch: tb, tb+4, tb+8, tb+12
    unsigned int uu[4];
    float s0[4], s1[4];
#pragma unroll
    for (int i = 0; i < 4; i++) {
      size_t token = (size_t)b * 12000 + slice * 240 + tb + i * 4;
      uu[i] = *(const unsigned int*)(X + token * 128 + 2 * lane);
      float x0 = bf2f((u16)(uu[i] & 0xffff)), x1 = bf2f((u16)(uu[i] >> 16));
      s0[i] = x0 + x1;
      s1[i] = x0 * x0 + x1 * x1;
    }
#pragma unroll
    for (int m = 32; m >= 1; m >>= 1) {
#pragma unroll
      for (int i = 0; i < 4; i++) {
        s0[i] += __shfl_xor(s0[i], m, 64);
        s1[i] += __shfl_xor(s1[i], m, 64);
      }
    }
#pragma unroll
    for (int i = 0; i < 4; i++) {
      float mean = s0[i] * (1.f / 128.f);
      float var = s1[i] * (1.f / 128.f) - mean * mean;
      float rstd = rsqrtf(var + 1e-5f);
      float x0 = bf2f((u16)(uu[i] & 0xffff)), x1 = bf2f((u16)(uu[i] >> 16));
      a0 += (x0 - mean) * rstd * nw0 + nb0;
      a1 += (x1 - mean) * rstd * nw1 + nb1;
    }
  }
  sacc[wv][2 * lane] = a0;
  sacc[wv][2 * lane + 1] = a1;
  __syncthreads();
  if (tid < 128) {
    float s = sacc[0][tid] + sacc[1][tid] + sacc[2][tid] + sacc[3][tid];
    atomicAdd(pool + b * 128 + tid, s);
  }
}

// ---------------- head: fp32 output ----------------
__global__ __launch_bounds__(256) void k_head(const float* __restrict__ pool,
                                              const u16* __restrict__ obs,
                                              const u16* __restrict__ vec,
                                              float* __restrict__ out) {
  const int b = blockIdx.x, o = threadIdx.x;
  float acc = bf2f(vec[VC_OBIAS + o]);
  for (int i = 0; i < 128; i++)
    acc += pool[b * 128 + i] * (1.f / 12000.f) * bf2f(vec[VC_OW + i * 256 + o]);
  for (int i = 0; i < 20; i++)
    acc += bf2f(obs[(size_t)b * 132020 + 132000 + i]) * bf2f(vec[VC_OW + (128 + i) * 256 + o]);
  out[b * 256 + o] = acc;
}

extern "C" void kernel_launch(void* const* d_in, const int* in_sizes, int n_in,
                              void* d_out, int out_size, void* d_ws, size_t ws_size,
                              hipStream_t stream) {
  u16* base  = (u16*)d_ws;
  int* flag  = (int*)d_ws;
  float* pool = (float*)((char*)d_ws + 16);
  u16* VEC   = base + 10000;
  u16* WT    = VEC + 45056;
  u16* OBSC  = WT + 393216;
  u16* X     = OBSC + 4224640;   // 49,152,000 u16
  u16* MT    = X + 49152000;     // 97*16384 = 1,589,248 u16 (~3.2 MB); total ~111 MB

  hipMemsetAsync(d_ws, 0, 16 + 32 * 128 * sizeof(float), stream);
  k_scan<<<1, 256, 0, stream>>>((const u16*)d_in[0], flag);

  // all 15 small VEC conversions in one launch (grid.y = segment).
  CvTab tab;
  const int cidx[15] = {1, 2, 3, 4, 6, 9, 10, 11, 13, 15, 16, 17, 7, 18, 19};
  const int coff[15] = {VC_PW, VC_PB, VC_N1W, VC_N1B, VC_QKVB, VC_PROJB, VC_N2W, VC_N2B,
                        VC_B1, VC_B2, VC_NFW, VC_NFB, VC_RPB, VC_OW, VC_OBIAS};
  const int cn[15]   = {1408, 128, 256, 256, 768, 256, 256, 256, 1024, 256, 128, 128,
                        1458, 37888, 256};
  for (int s = 0; s < 15; s++) { tab.src[s] = d_in[cidx[s]]; tab.off[s] = coff[s]; tab.n[s] = cn[s]; }
  k_convb<<<dim3(148, 15), 256, 0, stream>>>(tab, VEC, flag);
  k_mask<<<97, 256, 0, stream>>>(VEC, MT);
  k_conv<<<16504, 256, 0, stream>>>(d_in[0], OBSC, 4224640, flag);
  // R18: all 8 transposed-weight conversions in one launch (grid.y = segment).
  CtTab tt;
  for (int l = 0; l < 2; l++) {
    tt.src[l * 4 + 0] = d_in[5];  tt.K[l * 4 + 0] = 128; tt.N[l * 4 + 0] = 384;
    tt.eoff[l * 4 + 0] = l * 49152; tt.doff[l * 4 + 0] = WT_QKV + l * 49152;
    tt.src[l * 4 + 1] = d_in[8];  tt.K[l * 4 + 1] = 128; tt.N[l * 4 + 1] = 128;
    tt.eoff[l * 4 + 1] = l * 16384; tt.doff[l * 4 + 1] = WT_PROJ + l * 16384;
    tt.src[l * 4 + 2] = d_in[12]; tt.K[l * 4 + 2] = 128; tt.N[l * 4 + 2] = 512;
    tt.eoff[l * 4 + 2] = l * 65536; tt.doff[l * 4 + 2] = WT_W1 + l * 65536;
    tt.src[l * 4 + 3] = d_in[14]; tt.K[l * 4 + 3] = 512; tt.N[l * 4 + 3] = 128;
    tt.eoff[l * 4 + 3] = l * 65536; tt.doff[l * 4 + 3] = WT_W2 + l * 65536;
  }
  k_convT2b<<<dim3(256, 8), 256, 0, stream>>>(tt, WT, flag);

  k_patch<<<9600, 256, 0, stream>>>(OBSC, VEC, X);

  for (int l = 0; l < 2; l++) {
    const int shift = l ? 2 : 0;
    k_win<<<3072, 512, 0, stream>>>(X, WT + WT_QKV + l * 49152, WT + WT_PROJ + l * 16384,
                                    WT + WT_W1 + l * 65536, WT + WT_W2 + l * 65536,
                                    VEC + VC_QKVB + l * 384, VEC + VC_PROJB + l * 128,
                                    VEC + VC_N1W + l * 128, VEC + VC_N1B + l * 128,
                                    VEC + VC_N2W + l * 128, VEC + VC_N2B + l * 128,
                                    VEC + VC_B1 + l * 512, VEC + VC_B2 + l * 128,
                                    MT, shift, l);
  }

  k_pool<<<1600, 256, 0, stream>>>(X, VEC, pool);
  k_head<<<32, 256, 0, stream>>>(pool, OBSC, VEC, (float*)d_out);
}

// Round 19
// 1169.876 us; speedup vs baseline: 1.0325x; 1.0325x over previous
//
#include <hip/hip_runtime.h>
#include <hip/hip_bf16.h>

typedef unsigned short u16;
typedef short bf16x8 __attribute__((ext_vector_type(8)));
typedef float f32x4 __attribute__((ext_vector_type(4)));

#define SCALE_F 0.08838834764831845f

// VEC offsets (u16 elems)
#define VC_PW    0
#define VC_PB    1408
#define VC_N1W   1536
#define VC_N1B   1792
#define VC_QKVB  2048
#define VC_PROJB 2816
#define VC_N2W   3072
#define VC_N2B   3328
#define VC_B1    3584
#define VC_B2    4608
#define VC_NFW   4864
#define VC_NFB   4992
#define VC_RPB   5120
#define VC_OW    6592
#define VC_OBIAS 44480

// WT offsets (u16 elems) — transposed weights [N][K]
#define WT_QKV  0
#define WT_PROJ 98304
#define WT_W1   131072
#define WT_W2   262144

// MLP LDS (R17 layout, verified 500us): buf0 = sA[0,8192), buf1 = sC-as-u16.
// W1 chunk [0,4096) XOR-128; W2 chunk [4096,8192) XOR-32. sH = sA[8192,13312)
// stride-40. b1/b2 staged at sA[13312,13952) (LDS staging is load-bearing: R18's
// global-b1 variant cost ~18us/dispatch).
#define SH_OFF  8192
#define B1_OFF  13312
#define B2_OFF  13824

__device__ __forceinline__ float bf2f(u16 x) {
  union { unsigned int i; float f; } v; v.i = ((unsigned int)x) << 16; return v.f;
}
// HW bf16 convert (RTNE): compiler lowers pairs to v_cvt_pk_bf16_f32 (guide m240).
__device__ __forceinline__ u16 f2bf(float f) {
  __hip_bfloat16 h = __float2bfloat16(f);
  return __builtin_bit_cast(u16, h);
}
__device__ __forceinline__ unsigned int packbf(float a, float b) {
  return (unsigned int)f2bf(a) | ((unsigned int)f2bf(b) << 16);
}
__device__ __forceinline__ float wsum(float v) {
#pragma unroll
  for (int m = 32; m >= 1; m >>= 1) v += __shfl_xor(v, m, 64);
  return v;
}
// gelu with exp folded into exp2 (v_exp_f32 is native exp2).
__device__ __forceinline__ float gelu_f(float x) {
  float u = x * (-2.3022078f - 0.1029432f * x * x);
  float e = exp2f(u);
  return x * __builtin_amdgcn_rcpf(1.f + e);
}

// -------- dtype scan + decide (fused, LDS accumulators) --------
__global__ __launch_bounds__(256) void k_scan(const u16* __restrict__ raw, int* __restrict__ flag) {
  __shared__ int snan, sez;
  if (threadIdx.x == 0) { snan = 0; sez = 0; }
  __syncthreads();
  int nanc = 0, ez = 0;
  for (int i = threadIdx.x; i < 131072; i += 256) {
    u16 x = raw[i];
    if ((x & 0x7F80u) == 0x7F80u) nanc++;
    if (!(i & 1) && x == 0) ez++;
  }
  atomicAdd(&snan, nanc);
  atomicAdd(&sez, ez);
  __syncthreads();
  if (threadIdx.x == 0) flag[0] = (snan > 0 || sez > 49152) ? 1 : 0;
}

// -------- dual-mode converts --------
__global__ __launch_bounds__(256) void k_conv(const void* __restrict__ src, u16* __restrict__ dst,
                                              int n, const int* __restrict__ flag) {
  const int fl = *flag;
  int i = blockIdx.x * 256 + threadIdx.x;
  if (i < n) dst[i] = fl ? f2bf(((const float*)src)[i]) : ((const u16*)src)[i];
}
// all 15 small VEC conversions in ONE launch (grid.y = segment).
struct CvTab { const void* src[15]; int off[15]; int n[15]; };
__global__ __launch_bounds__(256) void k_convb(CvTab t, u16* __restrict__ dst,
                                               const int* __restrict__ flag) {
  const int fl = *flag;
  const int s = blockIdx.y;
  const int i = blockIdx.x * 256 + threadIdx.x;
  if (i < t.n[s]) {
    const void* src = t.src[s];
    dst[t.off[s] + i] = fl ? f2bf(((const float*)src)[i]) : ((const u16*)src)[i];
  }
}
// all 8 transposed-weight conversions in ONE launch (grid.y = segment).
struct CtTab { const void* src[8]; int K[8]; int N[8]; int eoff[8]; int doff[8]; };
__global__ __launch_bounds__(256) void k_convT2b(CtTab t, u16* __restrict__ WT,
                                                 const int* __restrict__ flag) {
  const int fl = *flag;
  const int s = blockIdx.y;
  const int id = blockIdx.x * 256 + threadIdx.x;
  const int K = t.K[s];
  if (id < K * t.N[s]) {
    int n = id / K, k = id % K;
    const void* src = t.src[s];
    int e = t.eoff[s] + k * t.N[s] + n;
    WT[t.doff[s] + id] = fl ? f2bf(((const float*)src)[e]) : ((const u16*)src)[e];
  }
}

// -------- precomputed attention bias tables --------
// TRANSPOSED layout MT[w][q*128+j]. w=96 -> layer 0.
__global__ __launch_bounds__(256) void k_mask(const u16* __restrict__ vec, u16* __restrict__ MT) {
  const int w = blockIdx.x;            // 0..95: layer-1 windows; 96: layer 0
  const bool bnd = (w < 96);
  const u16* rpb = vec + VC_RPB + (bnd ? 729 : 0);
  int wd = 0, wh = 0, ww = 0;
  if (bnd) { wd = w / 48; wh = (w >> 3) % 6; ww = w & 7; }
  for (int e = threadIdx.x; e < 16384; e += 256) {
    int j = e & 127, q = e >> 7;       // e = q*128 + j
    int qc = q > 124 ? 124 : q, jc = j > 124 ? 124 : j;
    int ldq = qc / 25, lhq = (qc / 5) % 5, lwq = qc % 5;
    int ldk = jc / 25, lhk = (jc / 5) % 5, lwk = jc % 5;
    float s = bf2f(rpb[((ldq - ldk + 4) * 9 + (lhq - lhk + 4)) * 9 + (lwq - lwk + 4)]);
    if (ldq < ldk) s -= 100.f;
    if (bnd) {
      int gdq = wd * 5 + ldq, ghq = wh * 5 + lhq, gwq = ww * 5 + lwq;
      int gdk = wd * 5 + ldk, ghk = wh * 5 + lhk, gwk = ww * 5 + lwk;
      int rq = (gdq < 5 ? 0 : (gdq < 8 ? 1 : 2)) * 9 + (ghq < 25 ? 0 : (ghq < 28 ? 1 : 2)) * 3 +
               (gwq < 35 ? 0 : (gwq < 38 ? 1 : 2));
      int rk = (gdk < 5 ? 0 : (gdk < 8 ? 1 : 2)) * 9 + (ghk < 25 ? 0 : (ghk < 28 ? 1 : 2)) * 3 +
               (gwk < 35 ? 0 : (gwk < 38 ? 1 : 2));
      if (rq != rk) s -= 100.f;
    }
    MT[(size_t)w * 16384 + e] = f2bf(s);
  }
}

// ---------------- patch embed (paired-channel outputs, 4B packed stores) ----------------
__global__ __launch_bounds__(256) void k_patch(const u16* __restrict__ obs,
                                               const u16* __restrict__ vec,
                                               u16* __restrict__ X) {
  __shared__ float vis[11][40];
  __shared__ float spw[11][128];
  __shared__ float spb[128];
  const int tid = threadIdx.x;
  const int bdh = blockIdx.x;
  const int b = bdh / 300, rem = bdh % 300;
  const int d = rem / 30, h = rem % 30;
  for (int i = tid; i < 1408; i += 256) spw[i >> 7][i & 127] = bf2f(vec[VC_PW + i]);
  if (tid < 128) spb[tid] = bf2f(vec[VC_PB + tid]);
  for (int i = tid; i < 440; i += 256) {
    int ch = i / 40, w = i % 40;
    vis[ch][w] = bf2f(obs[(size_t)b * 132020 + ((d * 11 + ch) * 30 + h) * 40 + w]);
  }
  __syncthreads();
  const size_t xbase = ((size_t)b * 12000 + d * 1200 + h * 40) * 128;
  for (int o2 = tid * 2; o2 < 40 * 128; o2 += 512) {
    int w = o2 >> 7, c = o2 & 127;          // c even
    float acc0 = spb[c], acc1 = spb[c + 1];
#pragma unroll
    for (int ch = 0; ch < 11; ch++) {
      float v = vis[ch][w];
      acc0 += v * spw[ch][c];
      acc1 += v * spw[ch][c + 1];
    }
    *(unsigned int*)(X + xbase + o2) = packbf(acc0, acc1);
  }
}

// One MLP double-buffer step with STATIC buffer pointers (unroll-x2; LDS b1).
#define MLP_STEP(BUFC, BUFN, HC, PF) {                                                          \
    uint4 w1n, w2n;                                                                             \
    const bool pf_ = (PF);                                                                      \
    if (pf_) {                                                                                  \
      w1n = *(const uint4*)(W1T + (size_t)(((HC) + 1) * 32 + (tid >> 4)) * 128 + (tid & 15) * 8); \
      w2n = *(const uint4*)(W2T + (size_t)(tid >> 2) * 512 + ((HC) + 1) * 32 + (tid & 3) * 8);  \
    }                                                                                           \
    f32x4 h4[2];                                                                                \
    _Pragma("unroll")                                                                           \
    for (int nt = 0; nt < 2; nt++)                                                              \
      _Pragma("unroll")                                                                         \
      for (int r = 0; r < 4; r++) h4[nt][r] = 0.f;                                              \
    _Pragma("unroll")                                                                           \
    for (int kc = 0; kc < 4; kc++) {                                                            \
      _Pragma("unroll")                                                                         \
      for (int nt = 0; nt < 2; nt++) {                                                          \
        int hrow = nt * 16 + m16;                                                               \
        bf16x8 af = *(const bf16x8*)((BUFC) + hrow * 128 + (((4 * kc + quad) ^ m16) << 3));     \
        h4[nt] = __builtin_amdgcn_mfma_f32_16x16x32_bf16(af, biM[kc], h4[nt], 0, 0, 0);         \
      }                                                                                         \
    }                                                                                           \
    _Pragma("unroll")                                                                           \
    for (int nt = 0; nt < 2; nt++) {                                                            \
      int hb = nt * 16 + quad * 4;                                                              \
      float g0 = gelu_f(h4[nt][0] + bf2f(sA[B1_OFF + (HC) * 32 + hb]));                         \
      float g1 = gelu_f(h4[nt][1] + bf2f(sA[B1_OFF + (HC) * 32 + hb + 1]));                     \
      float g2 = gelu_f(h4[nt][2] + bf2f(sA[B1_OFF + (HC) * 32 + hb + 2]));                     \
      float g3 = gelu_f(h4[nt][3] + bf2f(sA[B1_OFF + (HC) * 32 + hb + 3]));                     \
      uint2 pk;                                                                                 \
      pk.x = packbf(g0, g1);                                                                    \
      pk.y = packbf(g2, g3);                                                                    \
      *(uint2*)(sA + SH_OFF + tok * 40 + hb) = pk;                                              \
    }                                                                                           \
    {                                                                                           \
      bf16x8 bh = *(const bf16x8*)(sA + SH_OFF + tok * 40 + quad * 8);                          \
      _Pragma("unroll")                                                                         \
      for (int mt = 0; mt < 8; mt++) {                                                          \
        int oc = mt * 16 + m16;                                                                 \
        bf16x8 af = *(const bf16x8*)((BUFC) + 4096 + oc * 32 + ((quad ^ (oc & 3)) << 3));       \
        acc2[mt] = __builtin_amdgcn_mfma_f32_16x16x32_bf16(af, bh, acc2[mt], 0, 0, 0);          \
      }                                                                                         \
    }                                                                                           \
    if (pf_) {                                                                                  \
      int row_ = tid >> 4, g_ = tid & 15;                                                       \
      *(uint4*)((BUFN) + row_ * 128 + ((g_ ^ (row_ & 15)) << 3)) = w1n;                         \
      int row2_ = tid >> 2, g2_ = tid & 3;                                                      \
      *(uint4*)((BUFN) + 4096 + row2_ * 32 + ((g2_ ^ (row2_ & 3)) << 3)) = w2n;                 \
    }                                                                                           \
    __syncthreads();                                                                            \
  }

// ================== fused per-window BLOCK: LN1+QKV+attn+proj+res + LN2+MLP+res ==================
// One block per window (3072), 512 threads (8 waves), 80 KB LDS -> 2 blocks/CU.
// R17 k_win verbatim (verified 500us): channel-decomposed QKV AND proj; mask table;
// double-buffered MLP W (chunk 0 via barrier 7b); unroll-x2 MLP; LDS-staged b1/b2.
__global__ __launch_bounds__(512, 4) void k_win(u16* __restrict__ X,
                                                const u16* __restrict__ Wqkv,   // [384][128]
                                                const u16* __restrict__ Wproj,  // [128][128]
                                                const u16* __restrict__ W1T,    // [512][128]
                                                const u16* __restrict__ W2T,    // [128][512]
                                                const u16* __restrict__ qkvb,
                                                const u16* __restrict__ projb,
                                                const u16* __restrict__ n1w, const u16* __restrict__ n1b,
                                                const u16* __restrict__ n2w, const u16* __restrict__ n2b,
                                                const u16* __restrict__ b1, const u16* __restrict__ b2,
                                                const u16* __restrict__ MT,
                                                int shift, int boundary) {
  __shared__ u16 sA[128 * 128];   // Y -> K -> V^T -> proj-out -> {Wbuf0 | sH | b1b2}
  __shared__ u16 sB[128 * 128];   // Q -> P -> O -> sIn(LN2) -> mlp-out
  __shared__ uint2 sC[4 * 512];   // 16 KB: V stash (attn) -> Wbuf1 (MLP)
  u16* sCu = (u16*)sC;
  const int tid = threadIdx.x, lane = tid & 63, wv = tid >> 6;
  const int m16 = lane & 15, quad = lane >> 4;
  const int wing = blockIdx.x;
  const int b = wing / 96, winb = wing % 96;
  const int wd = winb / 48, wh = (winb >> 3) % 6, ww = winb & 7;
  const int tok = wv * 16 + m16;          // lane's token (0..127)
  const int tokc = tok > 124 ? 124 : tok;
  const u16* mtab = MT + (size_t)(boundary ? winb : 96) * 16384;

  // ---- LN1 + roll + gather: 4-row batches, 8 interleaved butterfly chains ----
  const float nw0 = bf2f(n1w[2 * lane]), nb0 = bf2f(n1b[2 * lane]);
  const float nw1 = bf2f(n1w[2 * lane + 1]), nb1 = bf2f(n1b[2 * lane + 1]);
  for (int rb = 0; rb < 16; rb += 4) {
    unsigned int uu[4];
    float s0[4], s1[4];
#pragma unroll
    for (int i = 0; i < 4; i++) {
      int row = wv * 16 + rb + i;
      int n = row > 124 ? 124 : row;
      int ld = n / 25, lh = (n / 5) % 5, lw = n % 5;
      int d = wd * 5 + ld + shift; if (d >= 10) d -= 10;
      int h = wh * 5 + lh + shift; if (h >= 30) h -= 30;
      int w2 = ww * 5 + lw + shift; if (w2 >= 40) w2 -= 40;
      const u16* xp = X + ((((size_t)b * 10 + d) * 30 + h) * 40 + w2) * 128;
      uu[i] = *(const unsigned int*)(xp + 2 * lane);
    }
#pragma unroll
    for (int i = 0; i < 4; i++) {
      float x0 = bf2f((u16)(uu[i] & 0xffff)), x1 = bf2f((u16)(uu[i] >> 16));
      s0[i] = x0 + x1;
      s1[i] = x0 * x0 + x1 * x1;
    }
#pragma unroll
    for (int m = 32; m >= 1; m >>= 1) {
#pragma unroll
      for (int i = 0; i < 4; i++) {
        s0[i] += __shfl_xor(s0[i], m, 64);
        s1[i] += __shfl_xor(s1[i], m, 64);
      }
    }
#pragma unroll
    for (int i = 0; i < 4; i++) {
      int r = rb + i;
      int row = wv * 16 + r;
      float mean = s0[i] * (1.f / 128.f);
      float var = s1[i] * (1.f / 128.f) - mean * mean;
      float rstd = rsqrtf(var + 1e-5f);
      float x0 = bf2f((u16)(uu[i] & 0xffff)), x1 = bf2f((u16)(uu[i] >> 16));
      float y0 = (x0 - mean) * rstd * nw0 + nb0;
      float y1 = (x1 - mean) * rstd * nw1 + nb1;
      *(unsigned int*)(sA + row * 128 + (((lane >> 2) ^ r) << 3) + ((2 * lane) & 7)) =
          packbf(y0, y1);
    }
  }
  __syncthreads();  // barrier 0: Y visible to all waves (channel-dec reads all rows)

  // ---- V (channel tile wv, all tokens): tt 0..3 -> sC stash, tt 4..7 -> vreg ----
  uint2 vreg[4];
  {
    bf16x8 aV[4];
#pragma unroll
    for (int kc = 0; kc < 4; kc++)
      aV[kc] = *(const bf16x8*)(Wqkv + (size_t)(256 + wv * 16 + m16) * 128 + kc * 32 + quad * 8);
    const int oc = 256 + wv * 16 + quad * 4;
    const float b0 = bf2f(qkvb[oc]), b1v = bf2f(qkvb[oc + 1]);
    const float b2v = bf2f(qkvb[oc + 2]), b3 = bf2f(qkvb[oc + 3]);
#pragma unroll
    for (int tt = 0; tt < 8; tt++) {
      f32x4 acc; acc[0] = 0.f; acc[1] = 0.f; acc[2] = 0.f; acc[3] = 0.f;
      int brow = tt * 16 + m16;
#pragma unroll
      for (int kc = 0; kc < 4; kc++) {
        bf16x8 bfr = *(const bf16x8*)(sA + brow * 128 + (((4 * kc + quad) ^ m16) << 3));
        acc = __builtin_amdgcn_mfma_f32_16x16x32_bf16(aV[kc], bfr, acc, 0, 0, 0);
      }
      uint2 pk;
      pk.x = packbf(acc[0] + b0, acc[1] + b1v);
      pk.y = packbf(acc[2] + b2v, acc[3] + b3);
      if (tt < 4) sC[tt * 512 + tid] = pk;
      else vreg[tt - 4] = pk;
    }
  }
  // ---- Q (channel tile wv, all tokens, scaled) -> sB[tok][wv-block] ----
  {
    bf16x8 aQ[4];
#pragma unroll
    for (int kc = 0; kc < 4; kc++)
      aQ[kc] = *(const bf16x8*)(Wqkv + (size_t)(wv * 16 + m16) * 128 + kc * 32 + quad * 8);
    const int oc = wv * 16 + quad * 4;
    const float b0 = bf2f(qkvb[oc]), b1v = bf2f(qkvb[oc + 1]);
    const float b2v = bf2f(qkvb[oc + 2]), b3 = bf2f(qkvb[oc + 3]);
#pragma unroll
    for (int tt = 0; tt < 8; tt++) {
      f32x4 acc; acc[0] = 0.f; acc[1] = 0.f; acc[2] = 0.f; acc[3] = 0.f;
      int brow = tt * 16 + m16;
#pragma unroll
      for (int kc = 0; kc < 4; kc++) {
        bf16x8 bfr = *(const bf16x8*)(sA + brow * 128 + (((4 * kc + quad) ^ m16) << 3));
        acc = __builtin_amdgcn_mfma_f32_16x16x32_bf16(aQ[kc], bfr, acc, 0, 0, 0);
      }
      uint2 pk;
      pk.x = packbf((acc[0] + b0) * SCALE_F, (acc[1] + b1v) * SCALE_F);
      pk.y = packbf((acc[2] + b2v) * SCALE_F, (acc[3] + b3) * SCALE_F);
      *(uint2*)(sB + brow * 128 + (((2 * wv + (quad >> 1)) ^ m16) << 3) + ((quad & 1) << 2)) = pk;
    }
  }
  // ---- K (channel tile wv, all tokens) -> kreg[8] (stored to sA after Y-reads barrier) ----
  uint2 kreg[8];
  {
    bf16x8 aK[4];
#pragma unroll
    for (int kc = 0; kc < 4; kc++)
      aK[kc] = *(const bf16x8*)(Wqkv + (size_t)(128 + wv * 16 + m16) * 128 + kc * 32 + quad * 8);
    const int oc = 128 + wv * 16 + quad * 4;
    const float b0 = bf2f(qkvb[oc]), b1v = bf2f(qkvb[oc + 1]);
    const float b2v = bf2f(qkvb[oc + 2]), b3 = bf2f(qkvb[oc + 3]);
#pragma unroll
    for (int tt = 0; tt < 8; tt++) {
      f32x4 acc; acc[0] = 0.f; acc[1] = 0.f; acc[2] = 0.f; acc[3] = 0.f;
      int brow = tt * 16 + m16;
#pragma unroll
      for (int kc = 0; kc < 4; kc++) {
        bf16x8 bfr = *(const bf16x8*)(sA + brow * 128 + (((4 * kc + quad) ^ m16) << 3));
        acc = __builtin_amdgcn_mfma_f32_16x16x32_bf16(aK[kc], bfr, acc, 0, 0, 0);
      }
      kreg[tt].x = packbf(acc[0] + b0, acc[1] + b1v);
      kreg[tt].y = packbf(acc[2] + b2v, acc[3] + b3);
    }
  }
  __syncthreads();  // barrier 1: all waves done reading Y from sA
  // ---- K store: sA[tok][wv-block] (overwrites Y) ----
#pragma unroll
  for (int tt = 0; tt < 8; tt++) {
    int brow = tt * 16 + m16;
    *(uint2*)(sA + brow * 128 + (((2 * wv + (quad >> 1)) ^ m16) << 3) + ((quad & 1) << 2)) = kreg[tt];
  }
  __syncthreads();  // barrier 2: K (and Q) visible to all waves

  // ---- S^T = K·Q^T ----
  f32x4 S[8];
#pragma unroll
  for (int jt = 0; jt < 8; jt++) { S[jt][0] = 0.f; S[jt][1] = 0.f; S[jt][2] = 0.f; S[jt][3] = 0.f; }
#pragma unroll
  for (int kc = 0; kc < 4; kc++) {
    bf16x8 qf = *(const bf16x8*)(sB + tok * 128 + (((4 * kc + quad) ^ m16) << 3));
#pragma unroll
    for (int jt = 0; jt < 8; jt++) {
      int row = jt * 16 + m16;
      bf16x8 kf = *(const bf16x8*)(sA + row * 128 + (((4 * kc + quad) ^ m16) << 3));
      S[jt] = __builtin_amdgcn_mfma_f32_16x16x32_bf16(kf, qf, S[jt], 0, 0, 0);
    }
  }
  // ---- bias from transposed table (uint2 loads) + softmax ----
  float mx = -1e30f;
#pragma unroll
  for (int jt = 0; jt < 8; jt++) {
    uint2 mv = *(const uint2*)(mtab + tokc * 128 + jt * 16 + quad * 4);
    u16 mb0 = (u16)(mv.x & 0xffff), mb1 = (u16)(mv.x >> 16);
    u16 mb2 = (u16)(mv.y & 0xffff), mb3 = (u16)(mv.y >> 16);
    float sv0 = S[jt][0] + bf2f(mb0);
    float sv1 = S[jt][1] + bf2f(mb1);
    float sv2 = S[jt][2] + bf2f(mb2);
    float sv3 = S[jt][3] + bf2f(mb3);
    int j0 = jt * 16 + quad * 4;
    if (j0 + 0 >= 125) sv0 = -1e30f;
    if (j0 + 1 >= 125) sv1 = -1e30f;
    if (j0 + 2 >= 125) sv2 = -1e30f;
    if (j0 + 3 >= 125) sv3 = -1e30f;
    S[jt][0] = sv0; S[jt][1] = sv1; S[jt][2] = sv2; S[jt][3] = sv3;
    mx = fmaxf(mx, fmaxf(fmaxf(sv0, sv1), fmaxf(sv2, sv3)));
  }
  mx = fmaxf(mx, __shfl_xor(mx, 16, 64));
  mx = fmaxf(mx, __shfl_xor(mx, 32, 64));
  float sm = 0.f;
#pragma unroll
  for (int jt = 0; jt < 8; jt++)
#pragma unroll
    for (int r = 0; r < 4; r++) {
      float e = __expf(S[jt][r] - mx);
      S[jt][r] = e;
      sm += e;
    }
  sm += __shfl_xor(sm, 16, 64);
  sm += __shfl_xor(sm, 32, 64);
  float inv = 1.f / sm;
  // P -> sB own rows (overwrites own Q)
#pragma unroll
  for (int jt = 0; jt < 8; jt++) {
    uint2 pk;
    pk.x = packbf(S[jt][0] * inv, S[jt][1] * inv);
    pk.y = packbf(S[jt][2] * inv, S[jt][3] * inv);
    *(uint2*)(sB + tok * 128 + (((2 * jt + (quad >> 1)) ^ m16) << 3) + ((quad & 1) << 2)) = pk;
  }
  __syncthreads();  // barrier 3: all waves done reading sA (K)
  // ---- V^T scatter into sA (overwrites K) ----
#pragma unroll
  for (int tt = 0; tt < 8; tt++) {
    uint2 vv = (tt < 4) ? sC[tt * 512 + tid] : vreg[tt - 4];
    int tokv = tt * 16 + m16;
    int c0 = wv * 16 + quad * 4;
    sA[(c0 + 0) * 128 + ((((tokv >> 3) ^ ((c0 + 0) & 15))) << 3) + (tokv & 7)] = (u16)(vv.x & 0xffffu);
    sA[(c0 + 1) * 128 + ((((tokv >> 3) ^ ((c0 + 1) & 15))) << 3) + (tokv & 7)] = (u16)(vv.x >> 16);
    sA[(c0 + 2) * 128 + ((((tokv >> 3) ^ ((c0 + 2) & 15))) << 3) + (tokv & 7)] = (u16)(vv.y & 0xffffu);
    sA[(c0 + 3) * 128 + ((((tokv >> 3) ^ ((c0 + 3) & 15))) << 3) + (tokv & 7)] = (u16)(vv.y >> 16);
  }
  __syncthreads();  // barrier 4: V^T visible to all waves
  // ---- O^T = VT·P ----
  f32x4 O[8];
#pragma unroll
  for (int ct = 0; ct < 8; ct++) { O[ct][0] = 0.f; O[ct][1] = 0.f; O[ct][2] = 0.f; O[ct][3] = 0.f; }
#pragma unroll
  for (int kc = 0; kc < 4; kc++) {
    bf16x8 pf = *(const bf16x8*)(sB + tok * 128 + (((4 * kc + quad) ^ m16) << 3));
#pragma unroll
    for (int ct = 0; ct < 8; ct++) {
      int c = ct * 16 + m16;
      bf16x8 vf = *(const bf16x8*)(sA + c * 128 + (((4 * kc + quad) ^ m16) << 3));
      O[ct] = __builtin_amdgcn_mfma_f32_16x16x32_bf16(vf, pf, O[ct], 0, 0, 0);
    }
  }
  // O -> sB own rows (overwrites own P) BEFORE barrier 5, so barrier 5 publishes O
#pragma unroll
  for (int ct = 0; ct < 8; ct++) {
    uint2 pk;
    pk.x = packbf(O[ct][0], O[ct][1]);
    pk.y = packbf(O[ct][2], O[ct][3]);
    *(uint2*)(sB + tok * 128 + (((2 * ct + (quad >> 1)) ^ m16) << 3) + ((quad & 1) << 2)) = pk;
  }
  __syncthreads();  // barrier 5: sA (V^T) reads done AND O (sB) visible to all waves

  // ---- proj (channel tile wv, all tokens) -> sA[tok][wv-block] (overwrites V^T) ----
  {
    bf16x8 aP[4];
#pragma unroll
    for (int kc = 0; kc < 4; kc++)
      aP[kc] = *(const bf16x8*)(Wproj + (size_t)(wv * 16 + m16) * 128 + kc * 32 + quad * 8);
    const int oc = wv * 16 + quad * 4;
    const float b0 = bf2f(projb[oc]), b1v = bf2f(projb[oc + 1]);
    const float b2v = bf2f(projb[oc + 2]), b3 = bf2f(projb[oc + 3]);
#pragma unroll
    for (int tt = 0; tt < 8; tt++) {
      f32x4 acc; acc[0] = 0.f; acc[1] = 0.f; acc[2] = 0.f; acc[3] = 0.f;
      int brow = tt * 16 + m16;
#pragma unroll
      for (int kc = 0; kc < 4; kc++) {
        bf16x8 bfr = *(const bf16x8*)(sB + brow * 128 + (((4 * kc + quad) ^ m16) << 3));
        acc = __builtin_amdgcn_mfma_f32_16x16x32_bf16(aP[kc], bfr, acc, 0, 0, 0);
      }
      uint2 pk;
      pk.x = packbf(acc[0] + b0, acc[1] + b1v);
      pk.y = packbf(acc[2] + b2v, acc[3] + b3);
      *(uint2*)(sA + brow * 128 + (((2 * wv + (quad >> 1)) ^ m16) << 3) + ((quad & 1) << 2)) = pk;
    }
  }
  __syncthreads();  // barrier 6: proj-out (sA) visible to all waves

  // ---- prefetch MLP chunk 0 into regs (latency hides under LN2 epilogue) ----
  uint4 w1r = *(const uint4*)(W1T + (size_t)(tid >> 4) * 128 + (tid & 15) * 8);
  uint4 w2r = *(const uint4*)(W2T + (size_t)(tid >> 2) * 512 + (tid & 3) * 8);
  // ---- fused epilogue: residual write + LN2 -> sIn(sB), 4-row batches ----
  const float w20 = bf2f(n2w[2 * lane]), v20 = bf2f(n2b[2 * lane]);
  const float w21 = bf2f(n2w[2 * lane + 1]), v21 = bf2f(n2b[2 * lane + 1]);
  for (int rb = 0; rb < 16; rb += 4) {
    float xn0[4], xn1[4], s0[4], s1[4];
#pragma unroll
    for (int i = 0; i < 4; i++) {
      int r = rb + i, row = wv * 16 + r;
      int n = row > 124 ? 124 : row;
      int ld = n / 25, lh = (n / 5) % 5, lw = n % 5;
      int d = wd * 5 + ld + shift; if (d >= 10) d -= 10;
      int h = wh * 5 + lh + shift; if (h >= 30) h -= 30;
      int w2 = ww * 5 + lw + shift; if (w2 >= 40) w2 -= 40;
      u16* xp = X + ((((size_t)b * 10 + d) * 30 + h) * 40 + w2) * 128;
      unsigned int pv = *(const unsigned int*)(sA + row * 128 + (((lane >> 2) ^ r) << 3) + ((2 * lane) & 7));
      unsigned int xo = *(const unsigned int*)(xp + 2 * lane);
      xn0[i] = bf2f((u16)(xo & 0xffff)) + bf2f((u16)(pv & 0xffff));
      xn1[i] = bf2f((u16)(xo >> 16)) + bf2f((u16)(pv >> 16));
      if (row < 125) *(unsigned int*)(xp + 2 * lane) = packbf(xn0[i], xn1[i]);
      s0[i] = xn0[i] + xn1[i];
      s1[i] = xn0[i] * xn0[i] + xn1[i] * xn1[i];
    }
#pragma unroll
    for (int m = 32; m >= 1; m >>= 1) {
#pragma unroll
      for (int i = 0; i < 4; i++) {
        s0[i] += __shfl_xor(s0[i], m, 64);
        s1[i] += __shfl_xor(s1[i], m, 64);
      }
    }
#pragma unroll
    for (int i = 0; i < 4; i++) {
      int r = rb + i, row = wv * 16 + r;
      float mean = s0[i] * (1.f / 128.f);
      float var = s1[i] * (1.f / 128.f) - mean * mean;
      float rstd = rsqrtf(var + 1e-5f);
      float y0 = (xn0[i] - mean) * rstd * w20 + v20;
      float y1 = (xn1[i] - mean) * rstd * w21 + v21;
      *(unsigned int*)(sB + row * 128 + (((lane >> 2) ^ r) << 3) + ((2 * lane) & 7)) =
          packbf(y0, y1);
    }
  }
  // ---- hoist MLP input fragments (own rows of sB; loop-invariant across hc) ----
  bf16x8 biM[4];
#pragma unroll
  for (int kc = 0; kc < 4; kc++)
    biM[kc] = *(const bf16x8*)(sB + tok * 128 + (((4 * kc + quad) ^ m16) << 3));
  __syncthreads();  // barrier 7: all sA (proj) reads done -> sA reusable for W staging

  // ---- write chunk 0 into buf0 (sA); stage b1/b2 into sA[13312,13952) ----
  {
    int row = tid >> 4, g = tid & 15;
    *(uint4*)(sA + row * 128 + ((g ^ (row & 15)) << 3)) = w1r;
    int row2 = tid >> 2, g2 = tid & 3;
    *(uint4*)(sA + 4096 + row2 * 32 + ((g2 ^ (row2 & 3)) << 3)) = w2r;
    sA[B1_OFF + tid] = b1[tid];
    if (tid < 128) sA[B2_OFF + tid] = b2[tid];
  }
  __syncthreads();  // barrier 7b: chunk 0 + bias tables visible

  // ---- MLP main loop: HC=32, 16 iters unrolled x2 (static buffers), 1 barrier/iter ----
  f32x4 acc2[8];
#pragma unroll
  for (int mt = 0; mt < 8; mt++)
#pragma unroll
    for (int r = 0; r < 4; r++) acc2[mt][r] = 0.f;
  for (int hc2 = 0; hc2 < 8; hc2++) {
    MLP_STEP(sA, sCu, 2 * hc2, true);
    MLP_STEP(sCu, sA, 2 * hc2 + 1, (hc2 < 7));
  }
  // ---- mlp-out (+bias) -> sB own rows; final residual RMW (rolled, guarded) ----
#pragma unroll
  for (int mt = 0; mt < 8; mt++) {
    int oc = mt * 16 + quad * 4;
    uint2 pk;
    pk.x = packbf(acc2[mt][0] + bf2f(sA[B2_OFF + oc]), acc2[mt][1] + bf2f(sA[B2_OFF + oc + 1]));
    pk.y = packbf(acc2[mt][2] + bf2f(sA[B2_OFF + oc + 2]), acc2[mt][3] + bf2f(sA[B2_OFF + oc + 3]));
    *(uint2*)(sB + tok * 128 + (((2 * mt + (quad >> 1)) ^ m16) << 3) + ((quad & 1) << 2)) = pk;
  }
  for (int r = 0; r < 16; r++) {
    int row = wv * 16 + r;
    if (row > 124) break;               // rows 125..127 duplicate token 124 (discard)
    int ld = row / 25, lh = (row / 5) % 5, lw = row % 5;
    int d = wd * 5 + ld + shift; if (d >= 10) d -= 10;
    int h = wh * 5 + lh + shift; if (h >= 30) h -= 30;
    int w2 = ww * 5 + lw + shift; if (w2 >= 40) w2 -= 40;
    u16* xp = X + ((((size_t)b * 10 + d) * 30 + h) * 40 + w2) * 128;
    unsigned int pv = *(const unsigned int*)(sB + row * 128 + (((lane >> 2) ^ r) << 3) + ((2 * lane) & 7));
    unsigned int xo = *(const unsigned int*)(xp + 2 * lane);
    float o0 = bf2f((u16)(xo & 0xffff)) + bf2f((u16)(pv & 0xffff));
    float o1 = bf2f((u16)(xo >> 16)) + bf2f((u16)(pv >> 16));
    *(unsigned int*)(xp + 2 * lane) = packbf(o0, o1);
  }
}

// ---------------- final LN + partial pooling (240-token slices, grid 1600) ----------------
__global__ __launch_bounds__(256) void k_pool(const u16* __restrict__ X, const u16* __restrict__ vec,
                                              float* __restrict__ pool) {
  __shared__ float sacc[4][128];
  const int tid = threadIdx.x, lane = tid & 63, wv = tid >> 6;
  const int b = blockIdx.x / 50, slice = blockIdx.x % 50;
  const float nw0 = bf2f(vec[VC_NFW + 2 * lane]), nb0 = bf2f(vec[VC_NFB + 2 * lane]);
  const float nw1 = bf2f(vec[VC_NFW + 2 * lane + 1]), nb1 = bf2f(vec[VC_NFB + 2 * lane + 1]);
  float a0 = 0.f, a1 = 0.f;
  for (int tb = wv; tb < 240; tb += 16) {      // 4 rows per batch: tb, tb+4, tb+8, tb+12
    unsigned int uu[4];
    float s0[4], s1[4];
#pragma unroll
    for (int i = 0; i < 4; i++) {
      size_t token = (size_t)b * 12000 + slice * 240 + tb + i * 4;
      uu[i] = *(const unsigned int*)(X + token * 128 + 2 * lane);
      float x0 = bf2f((u16)(uu[i] & 0xffff)), x1 = bf2f((u16)(uu[i] >> 16));
      s0[i] = x0 + x1;
      s1[i] = x0 * x0 + x1 * x1;
    }
#pragma unroll
    for (int m = 32; m >= 1; m >>= 1) {
#pragma unroll
      for (int i = 0; i < 4; i++) {
        s0[i] += __shfl_xor(s0[i], m, 64);
        s1[i] += __shfl_xor(s1[i], m, 64);
      }
    }
#pragma unroll
    for (int i = 0; i < 4; i++) {
      float mean = s0[i] * (1.f / 128.f);
      float var = s1[i] * (1.f / 128.f) - mean * mean;
      float rstd = rsqrtf(var + 1e-5f);
      float x0 = bf2f((u16)(uu[i] & 0xffff)), x1 = bf2f((u16)(uu[i] >> 16));
      a0 += (x0 - mean) * rstd * nw0 + nb0;
      a1 += (x1 - mean) * rstd * nw1 + nb1;
    }
  }
  sacc[wv][2 * lane] = a0;
  sacc[wv][2 * lane + 1] = a1;
  __syncthreads();
  if (tid < 128) {
    float s = sacc[0][tid] + sacc[1][tid] + sacc[2][tid] + sacc[3][tid];
    atomicAdd(pool + b * 128 + tid, s);
  }
}

// ---------------- head: fp32 output ----------------
__global__ __launch_bounds__(256) void k_head(const float* __restrict__ pool,
                                              const u16* __restrict__ obs,
                                              const u16* __restrict__ vec,
                                              float* __restrict__ out) {
  const int b = blockIdx.x, o = threadIdx.x;
  float acc = bf2f(vec[VC_OBIAS + o]);
  for (int i = 0; i < 128; i++)
    acc += pool[b * 128 + i] * (1.f / 12000.f) * bf2f(vec[VC_OW + i * 256 + o]);
  for (int i = 0; i < 20; i++)
    acc += bf2f(obs[(size_t)b * 132020 + 132000 + i]) * bf2f(vec[VC_OW + (128 + i) * 256 + o]);
  out[b * 256 + o] = acc;
}

extern "C" void kernel_launch(void* const* d_in, const int* in_sizes, int n_in,
                              void* d_out, int out_size, void* d_ws, size_t ws_size,
                              hipStream_t stream) {
  u16* base  = (u16*)d_ws;
  int* flag  = (int*)d_ws;
  float* pool = (float*)((char*)d_ws + 16);
  u16* VEC   = base + 10000;
  u16* WT    = VEC + 45056;
  u16* OBSC  = WT + 393216;
  u16* X     = OBSC + 4224640;   // 49,152,000 u16
  u16* MT    = X + 49152000;     // 97*16384 = 1,589,248 u16 (~3.2 MB); total ~111 MB

  hipMemsetAsync(d_ws, 0, 16 + 32 * 128 * sizeof(float), stream);
  k_scan<<<1, 256, 0, stream>>>((const u16*)d_in[0], flag);

  // all 15 small VEC conversions in one launch (grid.y = segment).
  CvTab tab;
  const int cidx[15] = {1, 2, 3, 4, 6, 9, 10, 11, 13, 15, 16, 17, 7, 18, 19};
  const int coff[15] = {VC_PW, VC_PB, VC_N1W, VC_N1B, VC_QKVB, VC_PROJB, VC_N2W, VC_N2B,
                        VC_B1, VC_B2, VC_NFW, VC_NFB, VC_RPB, VC_OW, VC_OBIAS};
  const int cn[15]   = {1408, 128, 256, 256, 768, 256, 256, 256, 1024, 256, 128, 128,
                        1458, 37888, 256};
  for (int s = 0; s < 15; s++) { tab.src[s] = d_in[cidx[s]]; tab.off[s] = coff[s]; tab.n[s] = cn[s]; }
  k_convb<<<dim3(148, 15), 256, 0, stream>>>(tab, VEC, flag);
  k_mask<<<97, 256, 0, stream>>>(VEC, MT);
  k_conv<<<16504, 256, 0, stream>>>(d_in[0], OBSC, 4224640, flag);
  // all 8 transposed-weight conversions in one launch (grid.y = segment).
  CtTab tt;
  for (int l = 0; l < 2; l++) {
    tt.src[l * 4 + 0] = d_in[5];  tt.K[l * 4 + 0] = 128; tt.N[l * 4 + 0] = 384;
    tt.eoff[l * 4 + 0] = l * 49152; tt.doff[l * 4 + 0] = WT_QKV + l * 49152;
    tt.src[l * 4 + 1] = d_in[8];  tt.K[l * 4 + 1] = 128; tt.N[l * 4 + 1] = 128;
    tt.eoff[l * 4 + 1] = l * 16384; tt.doff[l * 4 + 1] = WT_PROJ + l * 16384;
    tt.src[l * 4 + 2] = d_in[12]; tt.K[l * 4 + 2] = 128; tt.N[l * 4 + 2] = 512;
    tt.eoff[l * 4 + 2] = l * 65536; tt.doff[l * 4 + 2] = WT_W1 + l * 65536;
    tt.src[l * 4 + 3] = d_in[14]; tt.K[l * 4 + 3] = 512; tt.N[l * 4 + 3] = 128;
    tt.eoff[l * 4 + 3] = l * 65536; tt.doff[l * 4 + 3] = WT_W2 + l * 65536;
  }
  k_convT2b<<<dim3(256, 8), 256, 0, stream>>>(tt, WT, flag);

  k_patch<<<9600, 256, 0, stream>>>(OBSC, VEC, X);

  for (int l = 0; l < 2; l++) {
    const int shift = l ? 2 : 0;
    k_win<<<3072, 512, 0, stream>>>(X, WT + WT_QKV + l * 49152, WT + WT_PROJ + l * 16384,
                                    WT + WT_W1 + l * 65536, WT + WT_W2 + l * 65536,
                                    VEC + VC_QKVB + l * 384, VEC + VC_PROJB + l * 128,
                                    VEC + VC_N1W + l * 128, VEC + VC_N1B + l * 128,
                                    VEC + VC_N2W + l * 128, VEC + VC_N2B + l * 128,
                                    VEC + VC_B1 + l * 512, VEC + VC_B2 + l * 128,
                                    MT, shift, l);
  }

  k_pool<<<1600, 256, 0, stream>>>(X, VEC, pool);
  k_head<<<32, 256, 0, stream>>>(pool, OBSC, VEC, (float*)d_out);
}